// Round 6
// baseline (1191.864 us; speedup 1.0000x reference)
//
#include <hip/hip_runtime.h>

#define N_NODES 100000
#define N_EDGES 20000
#define NNZ_CNT 1000000
#define D 64
#define NCH 248
#define CHUNK 4096
#define NBE 625
#define NBV 782
#define NBT 1407

__device__ __forceinline__ unsigned short f2bf(float f) {
    unsigned int b = __float_as_uint(f);
    return (unsigned short)((b + 0x7fffu + ((b >> 16) & 1u)) >> 16);
}
__device__ __forceinline__ float bflo(unsigned int u) { return __uint_as_float(u << 16); }
__device__ __forceinline__ float bfhi(unsigned int u) { return __uint_as_float(u & 0xffff0000u); }

__global__ void k_combine(const float* __restrict__ W2, const float* __restrict__ b2,
                          const float* __restrict__ W,
                          float* __restrict__ A, float* __restrict__ B, float* __restrict__ c2) {
    __shared__ float W2s[64 * 129];
    __shared__ float Ws[64 * 65];
    __shared__ float b2s[64];
    int t = threadIdx.x;
    for (int i = t; i < 64 * 128; i += 256) W2s[(i >> 7) * 129 + (i & 127)] = W2[i];
    for (int i = t; i < 64 * 64; i += 256) Ws[(i >> 6) * 65 + (i & 63)] = W[i];
    if (t < 64) b2s[t] = b2[t];
    __syncthreads();
    int c = t & 63, kg = t >> 6;
    for (int kk = 0; kk < 16; ++kk) {
        int k = kg * 16 + kk;
        float a = 0.f, b = 0.f;
        for (int j = 0; j < 64; ++j) {
            float w = Ws[c * 65 + j];
            a += W2s[j * 129 + k] * w;
            b += W2s[j * 129 + 64 + k] * w;
        }
        A[k * 64 + c] = 0.5f * a;
        B[k * 64 + c] = 0.5f * b;
    }
    if (t < 64) {
        float s = 0.f;
        for (int j = 0; j < 64; ++j) s += b2s[j] * Ws[t * 65 + j];
        c2[t] = 0.5f * s;
    }
}

__global__ void __launch_bounds__(256) k_pre(const float* __restrict__ X, const float* __restrict__ X0,
                                             const float* __restrict__ W, const float* __restrict__ bw,
                                             unsigned short* __restrict__ X16, float* __restrict__ z0out) {
    __shared__ float Ws[64 * 65];
    __shared__ float x0s[256];
    int t = threadIdx.x;
    for (int i = t; i < 4096; i += 256) Ws[(i >> 6) * 65 + (i & 63)] = W[i];
    int w = t >> 6, cc = t & 63;
    float bwc = bw[cc];
    __syncthreads();
    for (int g = blockIdx.x; g < N_NODES / 4; g += gridDim.x) {
        int base = g * 256;
        X16[base + t] = f2bf(X[base + t]);
        x0s[t] = X0[base + t];
        __syncthreads();
        float acc = 0.f;
#pragma unroll
        for (int kk = 0; kk < 64; ++kk) acc += x0s[w * 64 + kk] * Ws[cc * 65 + kk];
        z0out[base + t] = 0.5f * acc + bwc;
        __syncthreads();
    }
}

__global__ void __launch_bounds__(256) k_hist(const int* __restrict__ vertex, const int* __restrict__ edges,
                                              int* __restrict__ He, int* __restrict__ Hv,
                                              int* __restrict__ btot) {
    __shared__ int hc[NBT];
    int t = threadIdx.x, c = blockIdx.x;
    for (int i = t; i < NBT; i += 256) hc[i] = 0;
    __syncthreads();
    int base = c * CHUNK;
    for (int k = 0; k < CHUNK / 256; ++k) {
        int i = base + k * 256 + t;
        if (i < NNZ_CNT) {
            atomicAdd(&hc[edges[i] >> 5], 1);
            atomicAdd(&hc[NBE + (vertex[i] >> 7)], 1);
        }
    }
    __syncthreads();
    for (int i = t; i < NBE; i += 256) { He[c * NBE + i] = hc[i]; atomicAdd(&btot[i], hc[i]); }
    for (int i = t; i < NBV; i += 256) { Hv[c * NBV + i] = hc[NBE + i]; atomicAdd(&btot[NBE + i], hc[NBE + i]); }
}

__global__ void __launch_bounds__(1024) k_scan_tot(const int* __restrict__ btot,
                                                   int* __restrict__ bstartE, int* __restrict__ bstartV) {
    __shared__ int s[NBT + 1];
    __shared__ int wsum[16];
    int t = threadIdx.x;
    int a0 = (2 * t < NBT) ? btot[2 * t] : 0;
    int a1 = (2 * t + 1 < NBT) ? btot[2 * t + 1] : 0;
    int sum = a0 + a1;
    int lane = t & 63, wid = t >> 6;
    int inc = sum;
    for (int d = 1; d < 64; d <<= 1) { int u = __shfl_up(inc, d); if (lane >= d) inc += u; }
    if (lane == 63) wsum[wid] = inc;
    __syncthreads();
    if (t < 16) {
        int u = wsum[t];
        for (int d = 1; d < 16; d <<= 1) { int x = __shfl_up(u, d); if (t >= d) u += x; }
        wsum[t] = u;
    }
    __syncthreads();
    int ex = inc - sum + (wid ? wsum[wid - 1] : 0);
    if (2 * t <= NBT) s[2 * t] = ex;
    if (2 * t + 1 <= NBT) s[2 * t + 1] = ex + a0;
    __syncthreads();
    int s625 = s[NBE];
    for (int j = t; j <= NBT; j += 1024) {
        int val = s[j];
        if (j <= NBE) bstartE[j] = val;
        if (j >= NBE) bstartV[j - NBE] = val - s625;
    }
}

__global__ void __launch_bounds__(256) k_scan_chunks(int* __restrict__ He, int* __restrict__ Hv,
                                                     const int* __restrict__ bstartE,
                                                     const int* __restrict__ bstartV) {
    int t = threadIdx.x;
    int* H; int col; int base; int nb;
    if ((int)blockIdx.x < NBE) { H = He; col = blockIdx.x; base = bstartE[col]; nb = NBE; }
    else { H = Hv; col = blockIdx.x - NBE; base = bstartV[col]; nb = NBV; }
    int val = (t < NCH) ? H[t * nb + col] : 0;
    int lane = t & 63, wid = t >> 6;
    int inc = val;
    for (int d = 1; d < 64; d <<= 1) { int u = __shfl_up(inc, d); if (lane >= d) inc += u; }
    __shared__ int ws4[4];
    if (lane == 63) ws4[wid] = inc;
    __syncthreads();
    if (t < 4) {
        int u = ws4[t];
        for (int d = 1; d < 4; d <<= 1) { int x = __shfl_up(u, d); if (t >= d) u += x; }
        ws4[t] = u;
    }
    __syncthreads();
    int ex = inc - val + (wid ? ws4[wid - 1] : 0);
    if (t < NCH) H[t * nb + col] = base + ex;
}

__global__ void __launch_bounds__(256) k_scatter(const int* __restrict__ vertex, const int* __restrict__ edges,
                                                 const int* __restrict__ He, const int* __restrict__ Hv,
                                                 unsigned int* __restrict__ pairE, unsigned int* __restrict__ pairV) {
    __shared__ int cur[NBT];
    int t = threadIdx.x, c = blockIdx.x;
    for (int i = t; i < NBE; i += 256) cur[i] = He[c * NBE + i];
    for (int i = t; i < NBV; i += 256) cur[NBE + i] = Hv[c * NBV + i];
    __syncthreads();
    int base = c * CHUNK;
    for (int k = 0; k < CHUNK / 256; ++k) {
        int i = base + k * 256 + t;
        if (i < NNZ_CNT) {
            unsigned int v = (unsigned int)vertex[i];
            unsigned int e = (unsigned int)edges[i];
            unsigned int u = (e << 17) | v;
            int pe = atomicAdd(&cur[e >> 5], 1);
            pairE[pe] = u;
            int pv = atomicAdd(&cur[NBE + (v >> 7)], 1);
            pairV[pv] = u;
        }
    }
}

__global__ void __launch_bounds__(256) k_edge(const unsigned int* __restrict__ pairE,
                                              const int* __restrict__ bstartE,
                                              const unsigned int* __restrict__ X16u,
                                              const float* __restrict__ W1, const float* __restrict__ b1,
                                              const float* __restrict__ Bg,
                                              float* __restrict__ Xe, unsigned short* __restrict__ Ye16) {
    __shared__ float acc[32 * 65];
    __shared__ float W1s[64 * 65];
    __shared__ float b1s[64];
    __shared__ int cnt[32];
    int t = threadIdx.x;
    int w = t >> 6, lane = t & 63, h = lane >> 5, q = lane & 31;
    for (int i = t; i < 32 * 65; i += 256) acc[i] = 0.f;
    if (t < 32) cnt[t] = 0;
    if (t < 64) b1s[t] = b1[t];
    for (int i = t; i < 4096; i += 256) W1s[(i >> 6) * 65 + (i & 63)] = W1[i];
    __syncthreads();
    int k = blockIdx.x;
    int e0 = k << 5;
    int beg = bstartE[k], end = bstartE[k + 1];
    int np = end - beg;
    for (int i = 2 * w; i < np; i += 16) {
        int iA = i + h, iB = i + 8 + h;
        bool bA = iA < np, bB = iB < np;
        unsigned int uA = bA ? pairE[beg + iA] : 0u;
        unsigned int uB = bB ? pairE[beg + iB] : 0u;
        unsigned int xA = bA ? X16u[(uA & 0x1FFFFu) * 32 + q] : 0u;
        unsigned int xB = bB ? X16u[(uB & 0x1FFFFu) * 32 + q] : 0u;
        if (bA) {
            int el = (int)(uA >> 17) - e0;
            atomicAdd(&acc[el * 65 + 2 * q], bflo(xA));
            atomicAdd(&acc[el * 65 + 2 * q + 1], bfhi(xA));
            if (q == 0) atomicAdd(&cnt[el], 1);
        }
        if (bB) {
            int el = (int)(uB >> 17) - e0;
            atomicAdd(&acc[el * 65 + 2 * q], bflo(xB));
            atomicAdd(&acc[el * 65 + 2 * q + 1], bfhi(xB));
            if (q == 0) atomicAdd(&cnt[el], 1);
        }
    }
    __syncthreads();
    int c = t & 63;
    float xr[8];
#pragma unroll
    for (int r = 0; r < 8; ++r) {
        int el = w + 4 * r;
        float s = 0.f;
#pragma unroll
        for (int kk = 0; kk < 64; ++kk) s += acc[el * 65 + kk] * W1s[c * 65 + kk];
        xr[r] = s + (float)cnt[el] * b1s[c];
        Xe[(e0 + el) * 64 + c] = xr[r];
    }
    __syncthreads();
#pragma unroll
    for (int r = 0; r < 8; ++r) acc[(w + 4 * r) * 65 + c] = xr[r];
    __syncthreads();
#pragma unroll
    for (int r = 0; r < 8; ++r) {
        int el = w + 4 * r;
        float s = 0.f;
#pragma unroll
        for (int kk = 0; kk < 64; ++kk) s += acc[el * 65 + kk] * Bg[kk * 64 + c];
        Ye16[(e0 + el) * 64 + c] = f2bf(s);
    }
}

__global__ void __launch_bounds__(256) k_node(const unsigned int* __restrict__ pairV,
                                              const int* __restrict__ bstartV,
                                              const unsigned int* __restrict__ Ye16u,
                                              const float* __restrict__ X,
                                              const float* __restrict__ Ag, const float* __restrict__ c2,
                                              float* __restrict__ out) {
    __shared__ float acc[128 * 65];
    __shared__ float xs[64 * 64];
    __shared__ float As[64 * 64];
    __shared__ float c2s[64];
    __shared__ int cnt[128];
    int t = threadIdx.x;
    int w = t >> 6, lane = t & 63, h = lane >> 5, q = lane & 31;
    for (int i = t; i < 128 * 65; i += 256) acc[i] = 0.f;
    if (t < 128) cnt[t] = 0;
    if (t < 64) c2s[t] = c2[t];
    for (int i = t; i < 4096; i += 256) As[i] = Ag[i];
    __syncthreads();
    int k = blockIdx.x;
    int v0 = k << 7;
    int beg = bstartV[k], end = bstartV[k + 1];
    int np = end - beg;
    for (int i = 2 * w; i < np; i += 16) {
        int iA = i + h, iB = i + 8 + h;
        bool bA = iA < np, bB = iB < np;
        unsigned int uA = bA ? pairV[beg + iA] : 0u;
        unsigned int uB = bB ? pairV[beg + iB] : 0u;
        unsigned int yA = bA ? Ye16u[(uA >> 17) * 32 + q] : 0u;
        unsigned int yB = bB ? Ye16u[(uB >> 17) * 32 + q] : 0u;
        if (bA) {
            int vl = (int)(uA & 0x1FFFFu) - v0;
            atomicAdd(&acc[vl * 65 + 2 * q], bflo(yA));
            atomicAdd(&acc[vl * 65 + 2 * q + 1], bfhi(yA));
            if (q == 0) atomicAdd(&cnt[vl], 1);
        }
        if (bB) {
            int vl = (int)(uB & 0x1FFFFu) - v0;
            atomicAdd(&acc[vl * 65 + 2 * q], bflo(yB));
            atomicAdd(&acc[vl * 65 + 2 * q + 1], bfhi(yB));
            if (q == 0) atomicAdd(&cnt[vl], 1);
        }
    }
    __syncthreads();
    int c = t & 63;
    for (int hh = 0; hh < 2; ++hh) {
        int vbase = v0 + hh * 64;
        for (int i = t; i < 4096; i += 256) {
            int vv = vbase + (i >> 6);
            xs[i] = (vv < N_NODES) ? X[vv * 64 + (i & 63)] : 0.f;
        }
        __syncthreads();
        for (int r = 0; r < 16; ++r) {
            int vll = w + 4 * r;
            int v = vbase + vll;
            if (v < N_NODES) {
                float p = 0.f;
#pragma unroll
                for (int kk = 0; kk < 64; ++kk) p += xs[vll * 64 + kk] * As[kk * 64 + c];
                int vl = vll + hh * 64;
                out[v * 64 + c] += (float)cnt[vl] * (p + c2s[c]) + acc[vl * 65 + c];
            }
        }
        __syncthreads();
    }
}

extern "C" void kernel_launch(void* const* d_in, const int* in_sizes, int n_in,
                              void* d_out, int out_size, void* d_ws, size_t ws_size,
                              hipStream_t stream) {
    const float* X  = (const float*)d_in[0];
    const float* X0 = (const float*)d_in[1];
    const int* vertex = (const int*)d_in[2];
    const int* edges  = (const int*)d_in[3];
    const float* W1w = (const float*)d_in[4];
    const float* W1b = (const float*)d_in[5];
    const float* W2w = (const float*)d_in[6];
    const float* W2bias = (const float*)d_in[7];
    const float* Ww  = (const float*)d_in[8];
    const float* Wbias = (const float*)d_in[9];

    float* out = (float*)d_out;
    float* Xe  = out + (size_t)N_NODES * D;

    char* ws = (char*)d_ws;
    unsigned short* X16 = (unsigned short*)(ws);
    unsigned short* Ye16 = (unsigned short*)(ws + 12800000);   // 2,560,000
    unsigned int* pairE = (unsigned int*)(ws + 15360000);      // 4,000,000
    unsigned int* pairV = (unsigned int*)(ws + 19360000);      // 4,000,000
    int* He      = (int*)(ws + 23360000);                      //   620,032
    int* Hv      = (int*)(ws + 23980032);                      //   775,808
    int* btot    = (int*)(ws + 24755840);                      //     5,632
    int* bstartE = (int*)(ws + 24761472);                      //     2,560
    int* bstartV = (int*)(ws + 24764032);                      //     3,328
    float* A     = (float*)(ws + 24767360);                    //    16,384
    float* Bm    = (float*)(ws + 24783744);                    //    16,384
    float* c2    = (float*)(ws + 24800128);                    //       256

    hipMemsetAsync(btot, 0, NBT * sizeof(int), stream);

    k_combine<<<1, 256, 0, stream>>>(W2w, W2bias, Ww, A, Bm, c2);
    k_pre<<<2048, 256, 0, stream>>>(X, X0, Ww, Wbias, X16, out);
    k_hist<<<NCH, 256, 0, stream>>>(vertex, edges, He, Hv, btot);
    k_scan_tot<<<1, 1024, 0, stream>>>(btot, bstartE, bstartV);
    k_scan_chunks<<<NBT, 256, 0, stream>>>(He, Hv, bstartE, bstartV);
    k_scatter<<<NCH, 256, 0, stream>>>(vertex, edges, He, Hv, pairE, pairV);
    k_edge<<<NBE, 256, 0, stream>>>(pairE, bstartE, (const unsigned int*)X16, W1w, W1b, Bm, Xe, Ye16);
    k_node<<<NBV, 256, 0, stream>>>(pairV, bstartV, (const unsigned int*)Ye16, X, A, c2, out);
}

// Round 7
// 381.479 us; speedup vs baseline: 3.1243x; 3.1243x over previous
//
#include <hip/hip_runtime.h>

#define N_NODES 100000
#define N_EDGES 20000
#define NNZ_CNT 1000000
#define D 64
#define NCH 245
#define CHUNK 4096
#define NBE 625      // edge buckets: 32 edges each (625*32 = 20000)
#define NBV 782      // vertex buckets: 128 vertices each (782*128 = 100096)
#define NBT 1407

__device__ __forceinline__ unsigned short f2bf(float f) {
    unsigned int b = __float_as_uint(f);
    return (unsigned short)((b + 0x7fffu + ((b >> 16) & 1u)) >> 16);   // RNE
}
__device__ __forceinline__ float bflo(unsigned int u) { return __uint_as_float(u << 16); }
__device__ __forceinline__ float bfhi(unsigned int u) { return __uint_as_float(u & 0xffff0000u); }

// ---------- A = 0.5*W2a^T W^T, B = 0.5*W2b^T W^T, c2 = 0.5*b2 W^T ----------
__global__ void k_combine(const float* __restrict__ W2, const float* __restrict__ b2,
                          const float* __restrict__ W,
                          float* __restrict__ A, float* __restrict__ B, float* __restrict__ c2) {
    __shared__ float W2s[64 * 129];
    __shared__ float Ws[64 * 65];
    __shared__ float b2s[64];
    int t = threadIdx.x;
    for (int i = t; i < 64 * 128; i += 256) W2s[(i >> 7) * 129 + (i & 127)] = W2[i];
    for (int i = t; i < 64 * 64; i += 256) Ws[(i >> 6) * 65 + (i & 63)] = W[i];
    if (t < 64) b2s[t] = b2[t];
    __syncthreads();
    int c = t & 63, kg = t >> 6;
    for (int kk = 0; kk < 16; ++kk) {
        int k = kg * 16 + kk;
        float a = 0.f, b = 0.f;
        for (int j = 0; j < 64; ++j) {
            float w = Ws[c * 65 + j];
            a += W2s[j * 129 + k] * w;
            b += W2s[j * 129 + 64 + k] * w;
        }
        A[k * 64 + c] = 0.5f * a;
        B[k * 64 + c] = 0.5f * b;
    }
    if (t < 64) {
        float s = 0.f;
        for (int j = 0; j < 64; ++j) s += b2s[j] * Ws[t * 65 + j];
        c2[t] = 0.5f * s;
    }
}

// ---------- per-chunk bucket histograms + global bucket totals ----------
__global__ void __launch_bounds__(256) k_hist(const int* __restrict__ vertex, const int* __restrict__ edges,
                                              int* __restrict__ He, int* __restrict__ Hv,
                                              int* __restrict__ btot) {
    __shared__ int hc[NBT];
    int t = threadIdx.x, c = blockIdx.x;
    for (int i = t; i < NBT; i += 256) hc[i] = 0;
    __syncthreads();
    int base = c * CHUNK;
    for (int k = 0; k < CHUNK / 256; ++k) {
        int i = base + k * 256 + t;
        if (i < NNZ_CNT) {
            atomicAdd(&hc[edges[i] >> 5], 1);
            atomicAdd(&hc[NBE + (vertex[i] >> 7)], 1);
        }
    }
    __syncthreads();
    for (int i = t; i < NBE; i += 256) { He[c * NBE + i] = hc[i]; atomicAdd(&btot[i], hc[i]); }
    for (int i = t; i < NBV; i += 256) { Hv[c * NBV + i] = hc[NBE + i]; atomicAdd(&btot[NBE + i], hc[NBE + i]); }
}

// ---------- exclusive scan of bucket totals -> bstartE/bstartV ----------
__global__ void __launch_bounds__(1024) k_scan_tot(const int* __restrict__ btot,
                                                   int* __restrict__ bstartE, int* __restrict__ bstartV) {
    __shared__ int s[NBT + 1];
    __shared__ int wsum[16];
    int t = threadIdx.x;
    int a0 = (2 * t < NBT) ? btot[2 * t] : 0;
    int a1 = (2 * t + 1 < NBT) ? btot[2 * t + 1] : 0;
    int sum = a0 + a1;
    int lane = t & 63, wid = t >> 6;
    int inc = sum;
    for (int d = 1; d < 64; d <<= 1) { int u = __shfl_up(inc, d); if (lane >= d) inc += u; }
    if (lane == 63) wsum[wid] = inc;
    __syncthreads();
    if (t < 16) {
        int u = wsum[t];
        for (int d = 1; d < 16; d <<= 1) { int x = __shfl_up(u, d); if (t >= d) u += x; }
        wsum[t] = u;
    }
    __syncthreads();
    int ex = inc - sum + (wid ? wsum[wid - 1] : 0);
    if (2 * t <= NBT) s[2 * t] = ex;
    if (2 * t + 1 <= NBT) s[2 * t + 1] = ex + a0;
    __syncthreads();
    int s625 = s[NBE];
    for (int j = t; j <= NBT; j += 1024) {
        int val = s[j];
        if (j <= NBE) bstartE[j] = val;
        if (j >= NBE) bstartV[j - NBE] = val - s625;
    }
}

// ---------- per-bucket scan over chunks -> global write bases ----------
__global__ void __launch_bounds__(256) k_scan_chunks(int* __restrict__ He, int* __restrict__ Hv,
                                                     const int* __restrict__ bstartE,
                                                     const int* __restrict__ bstartV) {
    int t = threadIdx.x;
    int* H; int col; int base; int nb;
    if ((int)blockIdx.x < NBE) { H = He; col = blockIdx.x; base = bstartE[col]; nb = NBE; }
    else { H = Hv; col = blockIdx.x - NBE; base = bstartV[col]; nb = NBV; }
    int val = (t < NCH) ? H[t * nb + col] : 0;
    int lane = t & 63, wid = t >> 6;
    int inc = val;
    for (int d = 1; d < 64; d <<= 1) { int u = __shfl_up(inc, d); if (lane >= d) inc += u; }
    __shared__ int ws4[4];
    if (lane == 63) ws4[wid] = inc;
    __syncthreads();
    if (t < 4) {
        int u = ws4[t];
        for (int d = 1; d < 4; d <<= 1) { int x = __shfl_up(u, d); if (t >= d) u += x; }
        ws4[t] = u;
    }
    __syncthreads();
    int ex = inc - val + (wid ? ws4[wid - 1] : 0);
    if (t < NCH) H[t * nb + col] = base + ex;
}

// ---------- bucketed scatter of packed pairs (e<<17)|v ----------
__global__ void __launch_bounds__(256) k_scatter(const int* __restrict__ vertex, const int* __restrict__ edges,
                                                 const int* __restrict__ He, const int* __restrict__ Hv,
                                                 unsigned int* __restrict__ pairE, unsigned int* __restrict__ pairV) {
    __shared__ int cur[NBT];
    int t = threadIdx.x, c = blockIdx.x;
    for (int i = t; i < NBE; i += 256) cur[i] = He[c * NBE + i];
    for (int i = t; i < NBV; i += 256) cur[NBE + i] = Hv[c * NBV + i];
    __syncthreads();
    int base = c * CHUNK;
    for (int k = 0; k < CHUNK / 256; ++k) {
        int i = base + k * 256 + t;
        if (i < NNZ_CNT) {
            unsigned int v = (unsigned int)vertex[i];
            unsigned int e = (unsigned int)edges[i];
            unsigned int u = (e << 17) | v;
            int pe = atomicAdd(&cur[e >> 5], 1);
            pairE[pe] = u;
            int pv = atomicAdd(&cur[NBE + (v >> 7)], 1);
            pairV[pv] = u;
        }
    }
}

// ---------- in-place LDS counting sort of an edge bucket; emits e_off, pairE -> vertex ids ----------
__global__ void __launch_bounds__(256) k_sortE(unsigned int* __restrict__ pairE,
                                               const int* __restrict__ bstartE, int* __restrict__ e_off) {
    __shared__ int sbuf[4096];
    __shared__ int hist[32], curr[32];
    int t = threadIdx.x, b = blockIdx.x;
    int beg = bstartE[b], np = bstartE[b + 1] - beg;
    if (np > 4096) np = 4096;   // statistically impossible; guards LDS OOB
    if (t < 32) hist[t] = 0;
    __syncthreads();
    for (int i = t; i < np; i += 256) atomicAdd(&hist[(pairE[beg + i] >> 17) & 31], 1);
    __syncthreads();
    if (t < 32) {
        int v = hist[t];
        int inc = v;
        for (int d = 1; d < 32; d <<= 1) { int u = __shfl_up(inc, d); if (t >= d) inc += u; }
        curr[t] = inc - v;
        e_off[b * 32 + t] = beg + inc - v;
    }
    if (b == NBE - 1 && t == 0) e_off[N_EDGES] = NNZ_CNT;
    __syncthreads();
    for (int i = t; i < np; i += 256) {
        unsigned int u = pairE[beg + i];
        int pos = atomicAdd(&curr[(u >> 17) & 31], 1);
        sbuf[pos] = (int)(u & 0x1FFFFu);
    }
    __syncthreads();
    for (int i = t; i < np; i += 256) pairE[beg + i] = (unsigned int)sbuf[i];
}

// ---------- in-place LDS counting sort of a vertex bucket; emits v_off, pairV -> edge ids ----------
__global__ void __launch_bounds__(256) k_sortV(unsigned int* __restrict__ pairV,
                                               const int* __restrict__ bstartV, int* __restrict__ v_off) {
    __shared__ int sbuf[4096];
    __shared__ int hist[128], scn[128], curr[128];
    int t = threadIdx.x, b = blockIdx.x;
    int beg = bstartV[b], np = bstartV[b + 1] - beg;
    if (np > 4096) np = 4096;
    if (t < 128) hist[t] = 0;
    __syncthreads();
    for (int i = t; i < np; i += 256) atomicAdd(&hist[pairV[beg + i] & 127], 1);
    __syncthreads();
    if (t < 128) scn[t] = hist[t];
    __syncthreads();
    for (int d = 1; d < 128; d <<= 1) {
        int val = 0;
        if (t < 128 && t >= d) val = scn[t - d];
        __syncthreads();
        if (t < 128) scn[t] += val;
        __syncthreads();
    }
    if (t < 128) {
        int ex = scn[t] - hist[t];
        curr[t] = ex;
        v_off[b * 128 + t] = beg + ex;
    }
    if (b == NBV - 1 && t == 0) v_off[NBV * 128] = NNZ_CNT;
    __syncthreads();
    for (int i = t; i < np; i += 256) {
        unsigned int u = pairV[beg + i];
        int pos = atomicAdd(&curr[u & 127], 1);
        sbuf[pos] = (int)(u >> 17);
    }
    __syncthreads();
    for (int i = t; i < np; i += 256) pairV[beg + i] = (unsigned int)sbuf[i];
}

// ---------- dense: z = deg*(x@A + c2) + 0.5*x0@W^T + bw -> OUT; X16 = bf16(X) ----------
__global__ void __launch_bounds__(256) k_pre(const float* __restrict__ X, const float* __restrict__ X0,
                                             const int* __restrict__ v_off,
                                             const float* __restrict__ A, const float* __restrict__ c2,
                                             const float* __restrict__ W, const float* __restrict__ bw,
                                             unsigned short* __restrict__ X16, float* __restrict__ zout) {
    __shared__ float As[64 * 65];
    __shared__ float Ws[64 * 65];
    __shared__ float xs[256], x0s[256];
    int t = threadIdx.x;
    for (int i = t; i < 4096; i += 256) {
        As[(i >> 6) * 65 + (i & 63)] = A[i];
        Ws[(i >> 6) * 65 + (i & 63)] = W[i];
    }
    int w = t >> 6, c = t & 63;
    float c2c = c2[c], bwc = bw[c];
    __syncthreads();
    for (int g = blockIdx.x; g < N_NODES / 4; g += gridDim.x) {
        int base = g * 256;
        float xv = X[base + t];
        X16[base + t] = f2bf(xv);
        xs[t] = xv;
        x0s[t] = X0[base + t];
        __syncthreads();
        int v = g * 4 + w;
        float d = (float)(v_off[v + 1] - v_off[v]);
        float accA = 0.f, acc0 = 0.f;
#pragma unroll
        for (int k = 0; k < 64; ++k) {
            accA += xs[w * 64 + k] * As[k * 65 + c];
            acc0 += x0s[w * 64 + k] * Ws[c * 65 + k];
        }
        zout[base + t] = d * (accA + c2c) + 0.5f * acc0 + bwc;
        __syncthreads();
    }
}

// ---------- per edge (wave): gather X16 rows, W1 transform, B transform ----------
__global__ void __launch_bounds__(256) k_edge(const int* __restrict__ e_off, const unsigned int* __restrict__ e_list,
                                              const unsigned int* __restrict__ X16u,
                                              const float* __restrict__ W1, const float* __restrict__ b1,
                                              const float* __restrict__ Bg,
                                              float* __restrict__ Xe, unsigned short* __restrict__ Ye16) {
    __shared__ float W1s[64 * 65];
    __shared__ float ses[4 * 64];
    __shared__ float xes[4 * 64];
    __shared__ float b1s[64];
    __shared__ int degs[4];
    int t = threadIdx.x;
    for (int i = t; i < 4096; i += 256) W1s[(i >> 6) * 65 + (i & 63)] = W1[i];
    if (t < 64) b1s[t] = b1[t];
    int w = t >> 6, lane = t & 63, h = lane >> 5, q = lane & 31;
    int e = blockIdx.x * 4 + w;
    int beg = e_off[e], end = e_off[e + 1];
    if (lane == 0) degs[w] = end - beg;
    float a0 = 0.f, a1 = 0.f;
    int j = beg;
    for (; j + 8 <= end; j += 8) {
        unsigned int v0 = e_list[j + h], v1 = e_list[j + 2 + h];
        unsigned int v2 = e_list[j + 4 + h], v3 = e_list[j + 6 + h];
        unsigned int u0 = X16u[v0 * 32 + q], u1 = X16u[v1 * 32 + q];
        unsigned int u2 = X16u[v2 * 32 + q], u3 = X16u[v3 * 32 + q];
        a0 += (bflo(u0) + bflo(u1)) + (bflo(u2) + bflo(u3));
        a1 += (bfhi(u0) + bfhi(u1)) + (bfhi(u2) + bfhi(u3));
    }
    for (; j + 2 <= end; j += 2) {
        unsigned int u = X16u[e_list[j + h] * 32 + q];
        a0 += bflo(u); a1 += bfhi(u);
    }
    if (j < end && h == 0) {
        unsigned int u = X16u[e_list[j] * 32 + q];
        a0 += bflo(u); a1 += bfhi(u);
    }
    a0 += __shfl_xor(a0, 32);
    a1 += __shfl_xor(a1, 32);
    if (h == 0) ((float2*)(ses + w * 64))[q] = make_float2(a0, a1);
    __syncthreads();
    int c = lane;
    float xe = 0.f;
#pragma unroll
    for (int k = 0; k < 64; ++k) xe += ses[w * 64 + k] * W1s[c * 65 + k];
    xe += (float)degs[w] * b1s[c];
    Xe[e * 64 + c] = xe;
    xes[w * 64 + c] = xe;
    __syncthreads();
    float ye = 0.f;
#pragma unroll
    for (int k = 0; k < 64; ++k) ye += xes[w * 64 + k] * Bg[k * 64 + c];
    Ye16[e * 64 + c] = f2bf(ye);
}

// ---------- per vertex (wave): out += sum of Ye16 rows ----------
__global__ void k_node(const int* __restrict__ v_off, const unsigned int* __restrict__ v_list,
                       const unsigned int* __restrict__ Ye16u, float* __restrict__ out) {
    int lane = threadIdx.x & 63;
    int v = (blockIdx.x * blockDim.x + threadIdx.x) >> 6;
    if (v >= N_NODES) return;
    int h = lane >> 5, q = lane & 31;
    int beg = v_off[v], end = v_off[v + 1];
    float a0 = 0.f, a1 = 0.f;
    int j = beg;
    for (; j + 8 <= end; j += 8) {
        unsigned int e0 = v_list[j + h], e1 = v_list[j + 2 + h];
        unsigned int e2 = v_list[j + 4 + h], e3 = v_list[j + 6 + h];
        unsigned int u0 = Ye16u[e0 * 32 + q], u1 = Ye16u[e1 * 32 + q];
        unsigned int u2 = Ye16u[e2 * 32 + q], u3 = Ye16u[e3 * 32 + q];
        a0 += (bflo(u0) + bflo(u1)) + (bflo(u2) + bflo(u3));
        a1 += (bfhi(u0) + bfhi(u1)) + (bfhi(u2) + bfhi(u3));
    }
    for (; j + 2 <= end; j += 2) {
        unsigned int u = Ye16u[v_list[j + h] * 32 + q];
        a0 += bflo(u); a1 += bfhi(u);
    }
    if (j < end && h == 0) {
        unsigned int u = Ye16u[v_list[j] * 32 + q];
        a0 += bflo(u); a1 += bfhi(u);
    }
    a0 += __shfl_xor(a0, 32);
    a1 += __shfl_xor(a1, 32);
    if (h == 0) {
        float2* o = (float2*)(out + (size_t)v * 64) + q;
        float2 z = *o;
        z.x += a0; z.y += a1;
        *o = z;
    }
}

extern "C" void kernel_launch(void* const* d_in, const int* in_sizes, int n_in,
                              void* d_out, int out_size, void* d_ws, size_t ws_size,
                              hipStream_t stream) {
    const float* X  = (const float*)d_in[0];
    const float* X0 = (const float*)d_in[1];
    const int* vertex = (const int*)d_in[2];
    const int* edges  = (const int*)d_in[3];
    const float* W1w = (const float*)d_in[4];
    const float* W1b = (const float*)d_in[5];
    const float* W2w = (const float*)d_in[6];
    const float* W2bias = (const float*)d_in[7];
    const float* Ww  = (const float*)d_in[8];
    const float* Wbias = (const float*)d_in[9];

    float* out = (float*)d_out;                 // N*64 (z -> final out)
    float* Xe  = out + (size_t)N_NODES * D;     // E*64 (second output)

    char* ws = (char*)d_ws;
    unsigned short* X16 = (unsigned short*)(ws);               // 12,800,000
    unsigned int* pairE = (unsigned int*)(ws + 12800000);      //  4,000,000 (-> e_list in place)
    unsigned int* pairV = (unsigned int*)(ws + 16800000);      //  4,000,000 (-> v_list in place)
    unsigned short* Ye16 = (unsigned short*)(ws + 20800000);   //  2,560,000
    int* He      = (int*)(ws + 23360000);                      //    612,608
    int* Hv      = (int*)(ws + 23972608);                      //    766,464
    int* btot    = (int*)(ws + 24739072);                      //      5,632
    int* bstartE = (int*)(ws + 24744704);                      //      2,560
    int* bstartV = (int*)(ws + 24747264);                      //      3,328
    int* e_off   = (int*)(ws + 24750592);                      //     80,128
    int* v_off   = (int*)(ws + 24830720);                      //    400,640
    float* A     = (float*)(ws + 25231360);                    //     16,384
    float* Bm    = (float*)(ws + 25247744);                    //     16,384
    float* c2    = (float*)(ws + 25264128);                    //        256

    hipMemsetAsync(btot, 0, NBT * sizeof(int), stream);

    k_combine<<<1, 256, 0, stream>>>(W2w, W2bias, Ww, A, Bm, c2);
    k_hist<<<NCH, 256, 0, stream>>>(vertex, edges, He, Hv, btot);
    k_scan_tot<<<1, 1024, 0, stream>>>(btot, bstartE, bstartV);
    k_scan_chunks<<<NBT, 256, 0, stream>>>(He, Hv, bstartE, bstartV);
    k_scatter<<<NCH, 256, 0, stream>>>(vertex, edges, He, Hv, pairE, pairV);
    k_sortE<<<NBE, 256, 0, stream>>>(pairE, bstartE, e_off);
    k_sortV<<<NBV, 256, 0, stream>>>(pairV, bstartV, v_off);
    k_pre<<<2048, 256, 0, stream>>>(X, X0, v_off, A, c2, Ww, Wbias, X16, out);
    k_edge<<<N_EDGES / 4, 256, 0, stream>>>(e_off, pairE, (const unsigned int*)X16,
                                            W1w, W1b, Bm, Xe, Ye16);
    k_node<<<(N_NODES * 64) / 256, 256, 0, stream>>>(v_off, pairV, (const unsigned int*)Ye16, out);
}

// Round 8
// 314.953 us; speedup vs baseline: 3.7843x; 1.2112x over previous
//
#include <hip/hip_runtime.h>

#define N_NODES 100000
#define N_EDGES 20000
#define NNZ_CNT 1000000
#define D 64
#define NCH 245
#define CHUNK 4096
#define NBE 625      // edge buckets: 32 edges each
#define NBV 782      // vertex buckets: 128 vertices each
#define NBT 1407

typedef short short8 __attribute__((ext_vector_type(8)));
typedef float f32x4 __attribute__((ext_vector_type(4)));

__device__ __forceinline__ unsigned short f2bf(float f) {
    unsigned int b = __float_as_uint(f);
    return (unsigned short)((b + 0x7fffu + ((b >> 16) & 1u)) >> 16);   // RNE
}
__device__ __forceinline__ float bflo(unsigned int u) { return __uint_as_float(u << 16); }
__device__ __forceinline__ float bfhi(unsigned int u) { return __uint_as_float(u & 0xffff0000u); }
__device__ __forceinline__ unsigned int pk2(float a, float b) {
    return (unsigned int)f2bf(a) | ((unsigned int)f2bf(b) << 16);
}

// ---------- combine epilogue matrices; emit c2, Bm(f32), and MFMA B-fragment packs ----------
// A = 0.5*W2a^T W^T, Bmat = 0.5*W2b^T W^T, c2 = 0.5*b2 W^T; packW = bf16(0.5*W^T) frag-packed
__global__ void k_combine(const float* __restrict__ W2, const float* __restrict__ b2,
                          const float* __restrict__ W,
                          float* __restrict__ Bm, float* __restrict__ c2,
                          unsigned short* __restrict__ packA16, unsigned short* __restrict__ packW16) {
    __shared__ float W2s[64 * 129];
    __shared__ float Ws[64 * 65];
    __shared__ float b2s[64];
    int t = threadIdx.x;
    for (int i = t; i < 64 * 128; i += 256) W2s[(i >> 7) * 129 + (i & 127)] = W2[i];
    for (int i = t; i < 64 * 64; i += 256) Ws[(i >> 6) * 65 + (i & 63)] = W[i];
    if (t < 64) b2s[t] = b2[t];
    __syncthreads();
    int c = t & 63, kg = t >> 6;
    for (int kk = 0; kk < 16; ++kk) {
        int k = kg * 16 + kk;
        float a = 0.f, b = 0.f;
        for (int j = 0; j < 64; ++j) {
            float w = Ws[c * 65 + j];
            a += W2s[j * 129 + k] * w;
            b += W2s[j * 129 + 64 + k] * w;
        }
        Bm[k * 64 + c] = 0.5f * b;
        // pack bf16(0.5*a) into fragment slot for matrix A
        int cb = c >> 4, kh = k >> 5, lane = ((k >> 3) & 3) * 16 + (c & 15), j = k & 7;
        packA16[((cb * 2 + kh) * 64 + lane) * 8 + j] = f2bf(0.5f * a);
    }
    // pack bf16(0.5*W^T): B-operand[k][c] = 0.5*W[c][k]
    for (int i = t; i < 4096; i += 256) {
        int c2i = i & 63, k = i >> 6;
        int cb = c2i >> 4, kh = k >> 5, lane = ((k >> 3) & 3) * 16 + (c2i & 15), j = k & 7;
        packW16[((cb * 2 + kh) * 64 + lane) * 8 + j] = f2bf(0.5f * Ws[c2i * 65 + k]);
    }
    if (t < 64) {
        float s = 0.f;
        for (int j = 0; j < 64; ++j) s += b2s[j] * Ws[t * 65 + j];
        c2[t] = 0.5f * s;
    }
}

// ---------- per-chunk bucket histograms + global bucket totals ----------
__global__ void __launch_bounds__(256) k_hist(const int* __restrict__ vertex, const int* __restrict__ edges,
                                              int* __restrict__ He, int* __restrict__ Hv,
                                              int* __restrict__ btot) {
    __shared__ int hc[NBT];
    int t = threadIdx.x, c = blockIdx.x;
    for (int i = t; i < NBT; i += 256) hc[i] = 0;
    __syncthreads();
    int base = c * CHUNK;
    for (int k = 0; k < CHUNK / 256; ++k) {
        int i = base + k * 256 + t;
        if (i < NNZ_CNT) {
            atomicAdd(&hc[edges[i] >> 5], 1);
            atomicAdd(&hc[NBE + (vertex[i] >> 7)], 1);
        }
    }
    __syncthreads();
    for (int i = t; i < NBE; i += 256) { He[c * NBE + i] = hc[i]; atomicAdd(&btot[i], hc[i]); }
    for (int i = t; i < NBV; i += 256) { Hv[c * NBV + i] = hc[NBE + i]; atomicAdd(&btot[NBE + i], hc[NBE + i]); }
}

// ---------- exclusive scan of bucket totals ----------
__global__ void __launch_bounds__(1024) k_scan_tot(const int* __restrict__ btot,
                                                   int* __restrict__ bstartE, int* __restrict__ bstartV) {
    __shared__ int s[NBT + 1];
    __shared__ int wsum[16];
    int t = threadIdx.x;
    int a0 = (2 * t < NBT) ? btot[2 * t] : 0;
    int a1 = (2 * t + 1 < NBT) ? btot[2 * t + 1] : 0;
    int sum = a0 + a1;
    int lane = t & 63, wid = t >> 6;
    int inc = sum;
    for (int d = 1; d < 64; d <<= 1) { int u = __shfl_up(inc, d); if (lane >= d) inc += u; }
    if (lane == 63) wsum[wid] = inc;
    __syncthreads();
    if (t < 16) {
        int u = wsum[t];
        for (int d = 1; d < 16; d <<= 1) { int x = __shfl_up(u, d); if (t >= d) u += x; }
        wsum[t] = u;
    }
    __syncthreads();
    int ex = inc - sum + (wid ? wsum[wid - 1] : 0);
    if (2 * t <= NBT) s[2 * t] = ex;
    if (2 * t + 1 <= NBT) s[2 * t + 1] = ex + a0;
    __syncthreads();
    int s625 = s[NBE];
    for (int j = t; j <= NBT; j += 1024) {
        int val = s[j];
        if (j <= NBE) bstartE[j] = val;
        if (j >= NBE) bstartV[j - NBE] = val - s625;
    }
}

// ---------- per-bucket scan over chunks -> global write bases ----------
__global__ void __launch_bounds__(256) k_scan_chunks(int* __restrict__ He, int* __restrict__ Hv,
                                                     const int* __restrict__ bstartE,
                                                     const int* __restrict__ bstartV) {
    int t = threadIdx.x;
    int* H; int col; int base; int nb;
    if ((int)blockIdx.x < NBE) { H = He; col = blockIdx.x; base = bstartE[col]; nb = NBE; }
    else { H = Hv; col = blockIdx.x - NBE; base = bstartV[col]; nb = NBV; }
    int val = (t < NCH) ? H[t * nb + col] : 0;
    int lane = t & 63, wid = t >> 6;
    int inc = val;
    for (int d = 1; d < 64; d <<= 1) { int u = __shfl_up(inc, d); if (lane >= d) inc += u; }
    __shared__ int ws4[4];
    if (lane == 63) ws4[wid] = inc;
    __syncthreads();
    if (t < 4) {
        int u = ws4[t];
        for (int d = 1; d < 4; d <<= 1) { int x = __shfl_up(u, d); if (t >= d) u += x; }
        ws4[t] = u;
    }
    __syncthreads();
    int ex = inc - val + (wid ? ws4[wid - 1] : 0);
    if (t < NCH) H[t * nb + col] = base + ex;
}

// ---------- bucketed scatter of packed pairs (e<<17)|v ----------
__global__ void __launch_bounds__(256) k_scatter(const int* __restrict__ vertex, const int* __restrict__ edges,
                                                 const int* __restrict__ He, const int* __restrict__ Hv,
                                                 unsigned int* __restrict__ pairE, unsigned int* __restrict__ pairV) {
    __shared__ int cur[NBT];
    int t = threadIdx.x, c = blockIdx.x;
    for (int i = t; i < NBE; i += 256) cur[i] = He[c * NBE + i];
    for (int i = t; i < NBV; i += 256) cur[NBE + i] = Hv[c * NBV + i];
    __syncthreads();
    int base = c * CHUNK;
    for (int k = 0; k < CHUNK / 256; ++k) {
        int i = base + k * 256 + t;
        if (i < NNZ_CNT) {
            unsigned int v = (unsigned int)vertex[i];
            unsigned int e = (unsigned int)edges[i];
            unsigned int u = (e << 17) | v;
            int pe = atomicAdd(&cur[e >> 5], 1);
            pairE[pe] = u;
            int pv = atomicAdd(&cur[NBE + (v >> 7)], 1);
            pairV[pv] = u;
        }
    }
}

// ---------- in-place LDS counting sort of an edge bucket ----------
__global__ void __launch_bounds__(256) k_sortE(unsigned int* __restrict__ pairE,
                                               const int* __restrict__ bstartE, int* __restrict__ e_off) {
    __shared__ int sbuf[4096];
    __shared__ int hist[32], curr[32];
    int t = threadIdx.x, b = blockIdx.x;
    int beg = bstartE[b], np = bstartE[b + 1] - beg;
    if (np > 4096) np = 4096;
    if (t < 32) hist[t] = 0;
    __syncthreads();
    for (int i = t; i < np; i += 256) atomicAdd(&hist[(pairE[beg + i] >> 17) & 31], 1);
    __syncthreads();
    if (t < 32) {
        int v = hist[t];
        int inc = v;
        for (int d = 1; d < 32; d <<= 1) { int u = __shfl_up(inc, d); if (t >= d) inc += u; }
        curr[t] = inc - v;
        e_off[b * 32 + t] = beg + inc - v;
    }
    if (b == NBE - 1 && t == 0) e_off[N_EDGES] = NNZ_CNT;
    __syncthreads();
    for (int i = t; i < np; i += 256) {
        unsigned int u = pairE[beg + i];
        int pos = atomicAdd(&curr[(u >> 17) & 31], 1);
        sbuf[pos] = (int)(u & 0x1FFFFu);
    }
    __syncthreads();
    for (int i = t; i < np; i += 256) pairE[beg + i] = (unsigned int)sbuf[i];
}

// ---------- in-place LDS counting sort of a vertex bucket ----------
__global__ void __launch_bounds__(256) k_sortV(unsigned int* __restrict__ pairV,
                                               const int* __restrict__ bstartV, int* __restrict__ v_off) {
    __shared__ int sbuf[4096];
    __shared__ int hist[128], scn[128], curr[128];
    int t = threadIdx.x, b = blockIdx.x;
    int beg = bstartV[b], np = bstartV[b + 1] - beg;
    if (np > 4096) np = 4096;
    if (t < 128) hist[t] = 0;
    __syncthreads();
    for (int i = t; i < np; i += 256) atomicAdd(&hist[pairV[beg + i] & 127], 1);
    __syncthreads();
    if (t < 128) scn[t] = hist[t];
    __syncthreads();
    for (int d = 1; d < 128; d <<= 1) {
        int val = 0;
        if (t < 128 && t >= d) val = scn[t - d];
        __syncthreads();
        if (t < 128) scn[t] += val;
        __syncthreads();
    }
    if (t < 128) {
        int ex = scn[t] - hist[t];
        curr[t] = ex;
        v_off[b * 128 + t] = beg + ex;
    }
    if (b == NBV - 1 && t == 0) v_off[NBV * 128] = NNZ_CNT;
    __syncthreads();
    for (int i = t; i < np; i += 256) {
        unsigned int u = pairV[beg + i];
        int pos = atomicAdd(&curr[u & 127], 1);
        sbuf[pos] = (int)(u >> 17);
    }
    __syncthreads();
    for (int i = t; i < np; i += 256) pairV[beg + i] = (unsigned int)sbuf[i];
}

// ---------- MFMA dense: z = deg*(x@A + c2) + x0@(0.5W^T) + bw -> OUT; X16 = bf16(X) ----------
// 64 nodes/block (4 waves x 16). A-frags from LDS bf16 rows; B-frags pre-packed.
__global__ void __launch_bounds__(256) k_pre(const float* __restrict__ X, const float* __restrict__ X0,
                                             const int* __restrict__ v_off,
                                             const unsigned short* __restrict__ packA16,
                                             const unsigned short* __restrict__ packW16,
                                             const float* __restrict__ c2, const float* __restrict__ bw,
                                             unsigned short* __restrict__ X16, float* __restrict__ zout) {
    __shared__ __align__(16) unsigned int bxu[64 * 36];    // bf16 rows of X, stride 36 uints
    __shared__ __align__(16) unsigned int bx0u[64 * 36];   // bf16 rows of X0
    __shared__ __align__(16) unsigned int pAs[2048];       // 8 frags x 64 lanes x 4 uint
    __shared__ __align__(16) unsigned int pWs[2048];
    __shared__ float degs[64];
    __shared__ float c2s[64], bws[64];
    int t = threadIdx.x;
    int gbase = blockIdx.x * 64;
    {
        const unsigned int* pa = (const unsigned int*)packA16;
        const unsigned int* pw = (const unsigned int*)packW16;
        for (int i = t; i < 2048; i += 256) { pAs[i] = pa[i]; pWs[i] = pw[i]; }
        if (t < 64) {
            c2s[t] = c2[t]; bws[t] = bw[t];
            int v = gbase + t;
            degs[t] = (v < N_NODES) ? (float)(v_off[v + 1] - v_off[v]) : 0.f;
        }
        // stage X, X0 as bf16 rows; write X16 (contiguous: thread t covers bytes t*32..)
        int row = t >> 2, seg = t & 3;
        int node = gbase + row;
        unsigned int us[8], us0[8];
        if (node < N_NODES) {
            const float4* sx = (const float4*)(X + (size_t)node * 64 + seg * 16);
            const float4* s0 = (const float4*)(X0 + (size_t)node * 64 + seg * 16);
#pragma unroll
            for (int i = 0; i < 4; ++i) {
                float4 f = sx[i];
                us[2 * i] = pk2(f.x, f.y); us[2 * i + 1] = pk2(f.z, f.w);
                float4 g = s0[i];
                us0[2 * i] = pk2(g.x, g.y); us0[2 * i + 1] = pk2(g.z, g.w);
            }
            unsigned int* xo = (unsigned int*)X16 + (size_t)node * 32 + seg * 8;
#pragma unroll
            for (int i = 0; i < 8; ++i) xo[i] = us[i];
        } else {
#pragma unroll
            for (int i = 0; i < 8; ++i) { us[i] = 0u; us0[i] = 0u; }
        }
#pragma unroll
        for (int i = 0; i < 8; ++i) {
            bxu[row * 36 + seg * 8 + i] = us[i];
            bx0u[row * 36 + seg * 8 + i] = us0[i];
        }
    }
    __syncthreads();
    int w = t >> 6, l = t & 63;
    int rbase = (l >> 4) * 4;          // C/D: row=(lane>>4)*4+reg, col=lane&15
    const short8* ax = (const short8*)(bxu + (w * 16 + (l & 15)) * 36 + (l >> 4) * 4);
    const short8* a0 = (const short8*)(bx0u + (w * 16 + (l & 15)) * 36 + (l >> 4) * 4);
    short8 ax0 = ax[0], ax1 = ax[4];   // kh=0 (+0B), kh=1 (+64B = 4 short8)
    short8 a00 = a0[0], a01 = a0[4];
#pragma unroll
    for (int cb = 0; cb < 4; ++cb) {
        f32x4 accA = {0.f, 0.f, 0.f, 0.f};
        f32x4 acc0 = {0.f, 0.f, 0.f, 0.f};
        const short8* bA0 = (const short8*)(pAs + ((cb * 2 + 0) * 64 + l) * 4);
        const short8* bA1 = (const short8*)(pAs + ((cb * 2 + 1) * 64 + l) * 4);
        const short8* bW0 = (const short8*)(pWs + ((cb * 2 + 0) * 64 + l) * 4);
        const short8* bW1 = (const short8*)(pWs + ((cb * 2 + 1) * 64 + l) * 4);
        accA = __builtin_amdgcn_mfma_f32_16x16x32_bf16(ax0, bA0[0], accA, 0, 0, 0);
        accA = __builtin_amdgcn_mfma_f32_16x16x32_bf16(ax1, bA1[0], accA, 0, 0, 0);
        acc0 = __builtin_amdgcn_mfma_f32_16x16x32_bf16(a00, bW0[0], acc0, 0, 0, 0);
        acc0 = __builtin_amdgcn_mfma_f32_16x16x32_bf16(a01, bW1[0], acc0, 0, 0, 0);
        int col = cb * 16 + (l & 15);
        float cc = c2s[col], bb = bws[col];
#pragma unroll
        for (int r = 0; r < 4; ++r) {
            int lrow = w * 16 + rbase + r;
            int node = gbase + lrow;
            if (node < N_NODES) {
                float z = degs[lrow] * (accA[r] + cc) + acc0[r] + bb;
                zout[(size_t)node * 64 + col] = z;
            }
        }
    }
}

// ---------- per edge (wave): gather X16 rows, W1 transform, B transform ----------
__global__ void __launch_bounds__(256) k_edge(const int* __restrict__ e_off, const unsigned int* __restrict__ e_list,
                                              const unsigned int* __restrict__ X16u,
                                              const float* __restrict__ W1, const float* __restrict__ b1,
                                              const float* __restrict__ Bg,
                                              float* __restrict__ Xe, unsigned short* __restrict__ Ye16) {
    __shared__ float W1s[64 * 65];
    __shared__ float ses[4 * 64];
    __shared__ float xes[4 * 64];
    __shared__ float b1s[64];
    __shared__ int degs[4];
    int t = threadIdx.x;
    for (int i = t; i < 4096; i += 256) W1s[(i >> 6) * 65 + (i & 63)] = W1[i];
    if (t < 64) b1s[t] = b1[t];
    int w = t >> 6, lane = t & 63, h = lane >> 5, q = lane & 31;
    int e = blockIdx.x * 4 + w;
    int beg = e_off[e], end = e_off[e + 1];
    if (lane == 0) degs[w] = end - beg;
    float a0 = 0.f, a1 = 0.f;
    int j = beg;
    for (; j + 8 <= end; j += 8) {
        unsigned int v0 = e_list[j + h], v1 = e_list[j + 2 + h];
        unsigned int v2 = e_list[j + 4 + h], v3 = e_list[j + 6 + h];
        unsigned int u0 = X16u[v0 * 32 + q], u1 = X16u[v1 * 32 + q];
        unsigned int u2 = X16u[v2 * 32 + q], u3 = X16u[v3 * 32 + q];
        a0 += (bflo(u0) + bflo(u1)) + (bflo(u2) + bflo(u3));
        a1 += (bfhi(u0) + bfhi(u1)) + (bfhi(u2) + bfhi(u3));
    }
    for (; j + 2 <= end; j += 2) {
        unsigned int u = X16u[e_list[j + h] * 32 + q];
        a0 += bflo(u); a1 += bfhi(u);
    }
    if (j < end && h == 0) {
        unsigned int u = X16u[e_list[j] * 32 + q];
        a0 += bflo(u); a1 += bfhi(u);
    }
    a0 += __shfl_xor(a0, 32);
    a1 += __shfl_xor(a1, 32);
    if (h == 0) ((float2*)(ses + w * 64))[q] = make_float2(a0, a1);
    __syncthreads();
    int c = lane;
    float xe = 0.f;
#pragma unroll
    for (int k = 0; k < 64; ++k) xe += ses[w * 64 + k] * W1s[c * 65 + k];
    xe += (float)degs[w] * b1s[c];
    Xe[e * 64 + c] = xe;
    xes[w * 64 + c] = xe;
    __syncthreads();
    float ye = 0.f;
#pragma unroll
    for (int k = 0; k < 64; ++k) ye += xes[w * 64 + k] * Bg[k * 64 + c];
    Ye16[e * 64 + c] = f2bf(ye);
}

// ---------- per vertex (wave): out += sum of Ye16 rows ----------
__global__ void k_node(const int* __restrict__ v_off, const unsigned int* __restrict__ v_list,
                       const unsigned int* __restrict__ Ye16u, float* __restrict__ out) {
    int lane = threadIdx.x & 63;
    int v = (blockIdx.x * blockDim.x + threadIdx.x) >> 6;
    if (v >= N_NODES) return;
    int h = lane >> 5, q = lane & 31;
    int beg = v_off[v], end = v_off[v + 1];
    float a0 = 0.f, a1 = 0.f;
    int j = beg;
    for (; j + 8 <= end; j += 8) {
        unsigned int e0 = v_list[j + h], e1 = v_list[j + 2 + h];
        unsigned int e2 = v_list[j + 4 + h], e3 = v_list[j + 6 + h];
        unsigned int u0 = Ye16u[e0 * 32 + q], u1 = Ye16u[e1 * 32 + q];
        unsigned int u2 = Ye16u[e2 * 32 + q], u3 = Ye16u[e3 * 32 + q];
        a0 += (bflo(u0) + bflo(u1)) + (bflo(u2) + bflo(u3));
        a1 += (bfhi(u0) + bfhi(u1)) + (bfhi(u2) + bfhi(u3));
    }
    for (; j + 2 <= end; j += 2) {
        unsigned int u = Ye16u[v_list[j + h] * 32 + q];
        a0 += bflo(u); a1 += bfhi(u);
    }
    if (j < end && h == 0) {
        unsigned int u = Ye16u[v_list[j] * 32 + q];
        a0 += bflo(u); a1 += bfhi(u);
    }
    a0 += __shfl_xor(a0, 32);
    a1 += __shfl_xor(a1, 32);
    if (h == 0) {
        float2* o = (float2*)(out + (size_t)v * 64) + q;
        float2 z = *o;
        z.x += a0; z.y += a1;
        *o = z;
    }
}

extern "C" void kernel_launch(void* const* d_in, const int* in_sizes, int n_in,
                              void* d_out, int out_size, void* d_ws, size_t ws_size,
                              hipStream_t stream) {
    const float* X  = (const float*)d_in[0];
    const float* X0 = (const float*)d_in[1];
    const int* vertex = (const int*)d_in[2];
    const int* edges  = (const int*)d_in[3];
    const float* W1w = (const float*)d_in[4];
    const float* W1b = (const float*)d_in[5];
    const float* W2w = (const float*)d_in[6];
    const float* W2bias = (const float*)d_in[7];
    const float* Ww  = (const float*)d_in[8];
    const float* Wbias = (const float*)d_in[9];

    float* out = (float*)d_out;                 // N*64 (z -> final out)
    float* Xe  = out + (size_t)N_NODES * D;     // E*64 (second output)

    char* ws = (char*)d_ws;
    unsigned short* X16 = (unsigned short*)(ws);               // 12,800,000
    unsigned int* pairE = (unsigned int*)(ws + 12800000);      //  4,000,000 (-> e_list)
    unsigned int* pairV = (unsigned int*)(ws + 16800000);      //  4,000,000 (-> v_list)
    unsigned short* Ye16 = (unsigned short*)(ws + 20800000);   //  2,560,000
    int* He      = (int*)(ws + 23360000);                      //    612,608
    int* Hv      = (int*)(ws + 23972608);                      //    766,464
    int* btot    = (int*)(ws + 24739072);                      //      5,632
    int* bstartE = (int*)(ws + 24744704);                      //      2,560
    int* bstartV = (int*)(ws + 24747264);                      //      3,328
    int* e_off   = (int*)(ws + 24750592);                      //     80,128
    int* v_off   = (int*)(ws + 24830720);                      //    400,640
    float* Bm    = (float*)(ws + 25231360);                    //     16,384
    float* c2    = (float*)(ws + 25247744);                    //        256
    unsigned short* packA16 = (unsigned short*)(ws + 25248000);//      8,192
    unsigned short* packW16 = (unsigned short*)(ws + 25256192);//      8,192

    hipMemsetAsync(btot, 0, NBT * sizeof(int), stream);

    k_combine<<<1, 256, 0, stream>>>(W2w, W2bias, Ww, Bm, c2, packA16, packW16);
    k_hist<<<NCH, 256, 0, stream>>>(vertex, edges, He, Hv, btot);
    k_scan_tot<<<1, 1024, 0, stream>>>(btot, bstartE, bstartV);
    k_scan_chunks<<<NBT, 256, 0, stream>>>(He, Hv, bstartE, bstartV);
    k_scatter<<<NCH, 256, 0, stream>>>(vertex, edges, He, Hv, pairE, pairV);
    k_sortE<<<NBE, 256, 0, stream>>>(pairE, bstartE, e_off);
    k_sortV<<<NBV, 256, 0, stream>>>(pairV, bstartV, v_off);
    k_pre<<<(N_NODES + 63) / 64, 256, 0, stream>>>(X, X0, v_off, packA16, packW16,
                                                   c2, Wbias, X16, out);
    k_edge<<<N_EDGES / 4, 256, 0, stream>>>(e_off, pairE, (const unsigned int*)X16,
                                            W1w, W1b, Bm, Xe, Ye16);
    k_node<<<(N_NODES * 64) / 256, 256, 0, stream>>>(v_off, pairV, (const unsigned int*)Ye16, out);
}

// Round 9
// 266.624 us; speedup vs baseline: 4.4702x; 1.1813x over previous
//
#include <hip/hip_runtime.h>

#define N_NODES 100000
#define N_EDGES 20000
#define NNZ_CNT 1000000
#define D 64
#define NCH 245
#define CHUNK 4096
#define NBE 625      // edge buckets: 32 edges each
#define NBV 782      // vertex buckets: 128 vertices each
#define NBT 1407

typedef short short8 __attribute__((ext_vector_type(8)));
typedef float f32x4 __attribute__((ext_vector_type(4)));

__device__ __forceinline__ unsigned short f2bf(float f) {
    unsigned int b = __float_as_uint(f);
    return (unsigned short)((b + 0x7fffu + ((b >> 16) & 1u)) >> 16);   // RNE
}
__device__ __forceinline__ float bflo(unsigned int u) { return __uint_as_float(u << 16); }
__device__ __forceinline__ float bfhi(unsigned int u) { return __uint_as_float(u & 0xffff0000u); }
__device__ __forceinline__ unsigned int pk2(float a, float b) {
    return (unsigned int)f2bf(a) | ((unsigned int)f2bf(b) << 16);
}

// ---------- combine epilogue matrices (parallel: 17 blocks) ----------
// blocks 0-15: A/Bm elements (thread = (k,c)); block 16: packW + c2
__global__ void __launch_bounds__(256) k_combine(const float* __restrict__ W2, const float* __restrict__ b2,
                                                 const float* __restrict__ W,
                                                 float* __restrict__ Bm, float* __restrict__ c2,
                                                 unsigned short* __restrict__ packA16,
                                                 unsigned short* __restrict__ packW16) {
    int b = blockIdx.x, t = threadIdx.x;
    if (b < 16) {
        __shared__ float Ws[64 * 65];
        for (int i = t; i < 4096; i += 256) Ws[(i >> 6) * 65 + (i & 63)] = W[i];
        __syncthreads();
        int idx = b * 256 + t;
        int k = idx >> 6, c = idx & 63;
        float a = 0.f, bb = 0.f;
#pragma unroll 8
        for (int j = 0; j < 64; ++j) {
            float w = Ws[c * 65 + j];
            a += W2[j * 128 + k] * w;
            bb += W2[j * 128 + 64 + k] * w;
        }
        Bm[k * 64 + c] = 0.5f * bb;
        int cb = c >> 4, kh = k >> 5, lane = ((k >> 3) & 3) * 16 + (c & 15), jj = k & 7;
        packA16[((cb * 2 + kh) * 64 + lane) * 8 + jj] = f2bf(0.5f * a);
    } else {
        // pack bf16(0.5*W^T): B-operand[k][c] = 0.5*W[c][k]
        for (int i = t; i < 4096; i += 256) {
            int c = i & 63, k = i >> 6;
            int cb = c >> 4, kh = k >> 5, lane = ((k >> 3) & 3) * 16 + (c & 15), jj = k & 7;
            packW16[((cb * 2 + kh) * 64 + lane) * 8 + jj] = f2bf(0.5f * W[c * 64 + k]);
        }
        if (t < 64) {
            float s = 0.f;
            for (int j = 0; j < 64; ++j) s += b2[j] * W[t * 64 + j];
            c2[t] = 0.5f * s;
        }
    }
}

// ---------- per-chunk bucket histograms + global bucket totals ----------
__global__ void __launch_bounds__(256) k_hist(const int* __restrict__ vertex, const int* __restrict__ edges,
                                              int* __restrict__ He, int* __restrict__ Hv,
                                              int* __restrict__ btot) {
    __shared__ int hc[NBT];
    int t = threadIdx.x, c = blockIdx.x;
    for (int i = t; i < NBT; i += 256) hc[i] = 0;
    __syncthreads();
    int base = c * CHUNK;
    for (int k = 0; k < CHUNK / 256; ++k) {
        int i = base + k * 256 + t;
        if (i < NNZ_CNT) {
            atomicAdd(&hc[edges[i] >> 5], 1);
            atomicAdd(&hc[NBE + (vertex[i] >> 7)], 1);
        }
    }
    __syncthreads();
    for (int i = t; i < NBE; i += 256) { He[c * NBE + i] = hc[i]; atomicAdd(&btot[i], hc[i]); }
    for (int i = t; i < NBV; i += 256) { Hv[c * NBV + i] = hc[NBE + i]; atomicAdd(&btot[NBE + i], hc[NBE + i]); }
}

// ---------- exclusive scan of bucket totals ----------
__global__ void __launch_bounds__(1024) k_scan_tot(const int* __restrict__ btot,
                                                   int* __restrict__ bstartE, int* __restrict__ bstartV) {
    __shared__ int s[NBT + 1];
    __shared__ int wsum[16];
    int t = threadIdx.x;
    int a0 = (2 * t < NBT) ? btot[2 * t] : 0;
    int a1 = (2 * t + 1 < NBT) ? btot[2 * t + 1] : 0;
    int sum = a0 + a1;
    int lane = t & 63, wid = t >> 6;
    int inc = sum;
    for (int d = 1; d < 64; d <<= 1) { int u = __shfl_up(inc, d); if (lane >= d) inc += u; }
    if (lane == 63) wsum[wid] = inc;
    __syncthreads();
    if (t < 16) {
        int u = wsum[t];
        for (int d = 1; d < 16; d <<= 1) { int x = __shfl_up(u, d); if (t >= d) u += x; }
        wsum[t] = u;
    }
    __syncthreads();
    int ex = inc - sum + (wid ? wsum[wid - 1] : 0);
    if (2 * t <= NBT) s[2 * t] = ex;
    if (2 * t + 1 <= NBT) s[2 * t + 1] = ex + a0;
    __syncthreads();
    int s625 = s[NBE];
    for (int j = t; j <= NBT; j += 1024) {
        int val = s[j];
        if (j <= NBE) bstartE[j] = val;
        if (j >= NBE) bstartV[j - NBE] = val - s625;
    }
}

// ---------- per-bucket scan over chunks -> global write bases ----------
__global__ void __launch_bounds__(256) k_scan_chunks(int* __restrict__ He, int* __restrict__ Hv,
                                                     const int* __restrict__ bstartE,
                                                     const int* __restrict__ bstartV) {
    int t = threadIdx.x;
    int* H; int col; int base; int nb;
    if ((int)blockIdx.x < NBE) { H = He; col = blockIdx.x; base = bstartE[col]; nb = NBE; }
    else { H = Hv; col = blockIdx.x - NBE; base = bstartV[col]; nb = NBV; }
    int val = (t < NCH) ? H[t * nb + col] : 0;
    int lane = t & 63, wid = t >> 6;
    int inc = val;
    for (int d = 1; d < 64; d <<= 1) { int u = __shfl_up(inc, d); if (lane >= d) inc += u; }
    __shared__ int ws4[4];
    if (lane == 63) ws4[wid] = inc;
    __syncthreads();
    if (t < 4) {
        int u = ws4[t];
        for (int d = 1; d < 4; d <<= 1) { int x = __shfl_up(u, d); if (t >= d) u += x; }
        ws4[t] = u;
    }
    __syncthreads();
    int ex = inc - val + (wid ? ws4[wid - 1] : 0);
    if (t < NCH) H[t * nb + col] = base + ex;
}

// ---------- bucketed scatter of packed pairs (e<<17)|v ----------
__global__ void __launch_bounds__(256) k_scatter(const int* __restrict__ vertex, const int* __restrict__ edges,
                                                 const int* __restrict__ He, const int* __restrict__ Hv,
                                                 unsigned int* __restrict__ pairE, unsigned int* __restrict__ pairV) {
    __shared__ int cur[NBT];
    int t = threadIdx.x, c = blockIdx.x;
    for (int i = t; i < NBE; i += 256) cur[i] = He[c * NBE + i];
    for (int i = t; i < NBV; i += 256) cur[NBE + i] = Hv[c * NBV + i];
    __syncthreads();
    int base = c * CHUNK;
    for (int k = 0; k < CHUNK / 256; ++k) {
        int i = base + k * 256 + t;
        if (i < NNZ_CNT) {
            unsigned int v = (unsigned int)vertex[i];
            unsigned int e = (unsigned int)edges[i];
            unsigned int u = (e << 17) | v;
            int pe = atomicAdd(&cur[e >> 5], 1);
            pairE[pe] = u;
            int pv = atomicAdd(&cur[NBE + (v >> 7)], 1);
            pairV[pv] = u;
        }
    }
}

// ---------- in-place LDS counting sort of an edge bucket ----------
__global__ void __launch_bounds__(256) k_sortE(unsigned int* __restrict__ pairE,
                                               const int* __restrict__ bstartE, int* __restrict__ e_off) {
    __shared__ int sbuf[4096];
    __shared__ int hist[32], curr[32];
    int t = threadIdx.x, b = blockIdx.x;
    int beg = bstartE[b], np = bstartE[b + 1] - beg;
    if (np > 4096) np = 4096;
    if (t < 32) hist[t] = 0;
    __syncthreads();
    for (int i = t; i < np; i += 256) atomicAdd(&hist[(pairE[beg + i] >> 17) & 31], 1);
    __syncthreads();
    if (t < 32) {
        int v = hist[t];
        int inc = v;
        for (int d = 1; d < 32; d <<= 1) { int u = __shfl_up(inc, d); if (t >= d) inc += u; }
        curr[t] = inc - v;
        e_off[b * 32 + t] = beg + inc - v;
    }
    if (b == NBE - 1 && t == 0) e_off[N_EDGES] = NNZ_CNT;
    __syncthreads();
    for (int i = t; i < np; i += 256) {
        unsigned int u = pairE[beg + i];
        int pos = atomicAdd(&curr[(u >> 17) & 31], 1);
        sbuf[pos] = (int)(u & 0x1FFFFu);
    }
    __syncthreads();
    for (int i = t; i < np; i += 256) pairE[beg + i] = (unsigned int)sbuf[i];
}

// ---------- in-place LDS counting sort of a vertex bucket ----------
__global__ void __launch_bounds__(256) k_sortV(unsigned int* __restrict__ pairV,
                                               const int* __restrict__ bstartV, int* __restrict__ v_off) {
    __shared__ int sbuf[4096];
    __shared__ int hist[128], scn[128], curr[128];
    int t = threadIdx.x, b = blockIdx.x;
    int beg = bstartV[b], np = bstartV[b + 1] - beg;
    if (np > 4096) np = 4096;
    if (t < 128) hist[t] = 0;
    __syncthreads();
    for (int i = t; i < np; i += 256) atomicAdd(&hist[pairV[beg + i] & 127], 1);
    __syncthreads();
    if (t < 128) scn[t] = hist[t];
    __syncthreads();
    for (int d = 1; d < 128; d <<= 1) {
        int val = 0;
        if (t < 128 && t >= d) val = scn[t - d];
        __syncthreads();
        if (t < 128) scn[t] += val;
        __syncthreads();
    }
    if (t < 128) {
        int ex = scn[t] - hist[t];
        curr[t] = ex;
        v_off[b * 128 + t] = beg + ex;
    }
    if (b == NBV - 1 && t == 0) v_off[NBV * 128] = NNZ_CNT;
    __syncthreads();
    for (int i = t; i < np; i += 256) {
        unsigned int u = pairV[beg + i];
        int pos = atomicAdd(&curr[u & 127], 1);
        sbuf[pos] = (int)(u >> 17);
    }
    __syncthreads();
    for (int i = t; i < np; i += 256) pairV[beg + i] = (unsigned int)sbuf[i];
}

// ---------- MFMA dense: z = deg*(x@A + c2) + x0@(0.5W^T) + bw -> OUT; X16 = bf16(X) ----------
__global__ void __launch_bounds__(256) k_pre(const float* __restrict__ X, const float* __restrict__ X0,
                                             const int* __restrict__ v_off,
                                             const unsigned short* __restrict__ packA16,
                                             const unsigned short* __restrict__ packW16,
                                             const float* __restrict__ c2, const float* __restrict__ bw,
                                             unsigned short* __restrict__ X16, float* __restrict__ zout) {
    __shared__ __align__(16) unsigned int bxu[64 * 36];
    __shared__ __align__(16) unsigned int bx0u[64 * 36];
    __shared__ __align__(16) unsigned int pAs[2048];
    __shared__ __align__(16) unsigned int pWs[2048];
    __shared__ float degs[64];
    __shared__ float c2s[64], bws[64];
    int t = threadIdx.x;
    int gbase = blockIdx.x * 64;
    {
        const unsigned int* pa = (const unsigned int*)packA16;
        const unsigned int* pw = (const unsigned int*)packW16;
        for (int i = t; i < 2048; i += 256) { pAs[i] = pa[i]; pWs[i] = pw[i]; }
        if (t < 64) {
            c2s[t] = c2[t]; bws[t] = bw[t];
            int v = gbase + t;
            degs[t] = (v < N_NODES) ? (float)(v_off[v + 1] - v_off[v]) : 0.f;
        }
        int row = t >> 2, seg = t & 3;
        int node = gbase + row;
        unsigned int us[8], us0[8];
        if (node < N_NODES) {
            const float4* sx = (const float4*)(X + (size_t)node * 64 + seg * 16);
            const float4* s0 = (const float4*)(X0 + (size_t)node * 64 + seg * 16);
#pragma unroll
            for (int i = 0; i < 4; ++i) {
                float4 f = sx[i];
                us[2 * i] = pk2(f.x, f.y); us[2 * i + 1] = pk2(f.z, f.w);
                float4 g = s0[i];
                us0[2 * i] = pk2(g.x, g.y); us0[2 * i + 1] = pk2(g.z, g.w);
            }
            unsigned int* xo = (unsigned int*)X16 + (size_t)node * 32 + seg * 8;
#pragma unroll
            for (int i = 0; i < 8; ++i) xo[i] = us[i];
        } else {
#pragma unroll
            for (int i = 0; i < 8; ++i) { us[i] = 0u; us0[i] = 0u; }
        }
#pragma unroll
        for (int i = 0; i < 8; ++i) {
            bxu[row * 36 + seg * 8 + i] = us[i];
            bx0u[row * 36 + seg * 8 + i] = us0[i];
        }
    }
    __syncthreads();
    int w = t >> 6, l = t & 63;
    int rbase = (l >> 4) * 4;
    const short8* ax = (const short8*)(bxu + (w * 16 + (l & 15)) * 36 + (l >> 4) * 4);
    const short8* a0 = (const short8*)(bx0u + (w * 16 + (l & 15)) * 36 + (l >> 4) * 4);
    short8 ax0 = ax[0], ax1 = ax[4];
    short8 a00 = a0[0], a01 = a0[4];
#pragma unroll
    for (int cb = 0; cb < 4; ++cb) {
        f32x4 accA = {0.f, 0.f, 0.f, 0.f};
        f32x4 acc0 = {0.f, 0.f, 0.f, 0.f};
        const short8* bA0 = (const short8*)(pAs + ((cb * 2 + 0) * 64 + l) * 4);
        const short8* bA1 = (const short8*)(pAs + ((cb * 2 + 1) * 64 + l) * 4);
        const short8* bW0 = (const short8*)(pWs + ((cb * 2 + 0) * 64 + l) * 4);
        const short8* bW1 = (const short8*)(pWs + ((cb * 2 + 1) * 64 + l) * 4);
        accA = __builtin_amdgcn_mfma_f32_16x16x32_bf16(ax0, bA0[0], accA, 0, 0, 0);
        accA = __builtin_amdgcn_mfma_f32_16x16x32_bf16(ax1, bA1[0], accA, 0, 0, 0);
        acc0 = __builtin_amdgcn_mfma_f32_16x16x32_bf16(a00, bW0[0], acc0, 0, 0, 0);
        acc0 = __builtin_amdgcn_mfma_f32_16x16x32_bf16(a01, bW1[0], acc0, 0, 0, 0);
        int col = cb * 16 + (l & 15);
        float cc = c2s[col], bb = bws[col];
#pragma unroll
        for (int r = 0; r < 4; ++r) {
            int lrow = w * 16 + rbase + r;
            int node = gbase + lrow;
            if (node < N_NODES) {
                float z = degs[lrow] * (accA[r] + cc) + acc0[r] + bb;
                zout[(size_t)node * 64 + col] = z;
            }
        }
    }
}

// ---------- per edge (wave): gather X16 rows, W1 transform, B transform ----------
__global__ void __launch_bounds__(256) k_edge(const int* __restrict__ e_off, const unsigned int* __restrict__ e_list,
                                              const unsigned int* __restrict__ X16u,
                                              const float* __restrict__ W1, const float* __restrict__ b1,
                                              const float* __restrict__ Bg,
                                              float* __restrict__ Xe, unsigned short* __restrict__ Ye16) {
    __shared__ float W1s[64 * 65];
    __shared__ float ses[4 * 64];
    __shared__ float xes[4 * 64];
    __shared__ float b1s[64];
    __shared__ int degs[4];
    int t = threadIdx.x;
    for (int i = t; i < 4096; i += 256) W1s[(i >> 6) * 65 + (i & 63)] = W1[i];
    if (t < 64) b1s[t] = b1[t];
    int w = t >> 6, lane = t & 63, h = lane >> 5, q = lane & 31;
    int e = blockIdx.x * 4 + w;
    int beg = e_off[e], end = e_off[e + 1];
    if (lane == 0) degs[w] = end - beg;
    float a0 = 0.f, a1 = 0.f;
    int j = beg;
    for (; j + 8 <= end; j += 8) {
        unsigned int v0 = e_list[j + h], v1 = e_list[j + 2 + h];
        unsigned int v2 = e_list[j + 4 + h], v3 = e_list[j + 6 + h];
        unsigned int u0 = X16u[v0 * 32 + q], u1 = X16u[v1 * 32 + q];
        unsigned int u2 = X16u[v2 * 32 + q], u3 = X16u[v3 * 32 + q];
        a0 += (bflo(u0) + bflo(u1)) + (bflo(u2) + bflo(u3));
        a1 += (bfhi(u0) + bfhi(u1)) + (bfhi(u2) + bfhi(u3));
    }
    for (; j + 2 <= end; j += 2) {
        unsigned int u = X16u[e_list[j + h] * 32 + q];
        a0 += bflo(u); a1 += bfhi(u);
    }
    if (j < end && h == 0) {
        unsigned int u = X16u[e_list[j] * 32 + q];
        a0 += bflo(u); a1 += bfhi(u);
    }
    a0 += __shfl_xor(a0, 32);
    a1 += __shfl_xor(a1, 32);
    if (h == 0) ((float2*)(ses + w * 64))[q] = make_float2(a0, a1);
    __syncthreads();
    int c = lane;
    float xe = 0.f;
#pragma unroll
    for (int k = 0; k < 64; ++k) xe += ses[w * 64 + k] * W1s[c * 65 + k];
    xe += (float)degs[w] * b1s[c];
    Xe[e * 64 + c] = xe;
    xes[w * 64 + c] = xe;
    __syncthreads();
    float ye = 0.f;
#pragma unroll
    for (int k = 0; k < 64; ++k) ye += xes[w * 64 + k] * Bg[k * 64 + c];
    Ye16[e * 64 + c] = f2bf(ye);
}

// ---------- per vertex (wave): out += sum of Ye16 rows ----------
__global__ void k_node(const int* __restrict__ v_off, const unsigned int* __restrict__ v_list,
                       const unsigned int* __restrict__ Ye16u, float* __restrict__ out) {
    int lane = threadIdx.x & 63;
    int v = (blockIdx.x * blockDim.x + threadIdx.x) >> 6;
    if (v >= N_NODES) return;
    int h = lane >> 5, q = lane & 31;
    int beg = v_off[v], end = v_off[v + 1];
    float a0 = 0.f, a1 = 0.f;
    int j = beg;
    for (; j + 8 <= end; j += 8) {
        unsigned int e0 = v_list[j + h], e1 = v_list[j + 2 + h];
        unsigned int e2 = v_list[j + 4 + h], e3 = v_list[j + 6 + h];
        unsigned int u0 = Ye16u[e0 * 32 + q], u1 = Ye16u[e1 * 32 + q];
        unsigned int u2 = Ye16u[e2 * 32 + q], u3 = Ye16u[e3 * 32 + q];
        a0 += (bflo(u0) + bflo(u1)) + (bflo(u2) + bflo(u3));
        a1 += (bfhi(u0) + bfhi(u1)) + (bfhi(u2) + bfhi(u3));
    }
    for (; j + 2 <= end; j += 2) {
        unsigned int u = Ye16u[v_list[j + h] * 32 + q];
        a0 += bflo(u); a1 += bfhi(u);
    }
    if (j < end && h == 0) {
        unsigned int u = Ye16u[v_list[j] * 32 + q];
        a0 += bflo(u); a1 += bfhi(u);
    }
    a0 += __shfl_xor(a0, 32);
    a1 += __shfl_xor(a1, 32);
    if (h == 0) {
        float2* o = (float2*)(out + (size_t)v * 64) + q;
        float2 z = *o;
        z.x += a0; z.y += a1;
        *o = z;
    }
}

extern "C" void kernel_launch(void* const* d_in, const int* in_sizes, int n_in,
                              void* d_out, int out_size, void* d_ws, size_t ws_size,
                              hipStream_t stream) {
    const float* X  = (const float*)d_in[0];
    const float* X0 = (const float*)d_in[1];
    const int* vertex = (const int*)d_in[2];
    const int* edges  = (const int*)d_in[3];
    const float* W1w = (const float*)d_in[4];
    const float* W1b = (const float*)d_in[5];
    const float* W2w = (const float*)d_in[6];
    const float* W2bias = (const float*)d_in[7];
    const float* Ww  = (const float*)d_in[8];
    const float* Wbias = (const float*)d_in[9];

    float* out = (float*)d_out;                 // N*64 (z -> final out)
    float* Xe  = out + (size_t)N_NODES * D;     // E*64 (second output)

    char* ws = (char*)d_ws;
    unsigned short* X16 = (unsigned short*)(ws);               // 12,800,000
    unsigned int* pairE = (unsigned int*)(ws + 12800000);      //  4,000,000 (-> e_list)
    unsigned int* pairV = (unsigned int*)(ws + 16800000);      //  4,000,000 (-> v_list)
    unsigned short* Ye16 = (unsigned short*)(ws + 20800000);   //  2,560,000
    int* He      = (int*)(ws + 23360000);                      //    612,608
    int* Hv      = (int*)(ws + 23972608);                      //    766,464
    int* btot    = (int*)(ws + 24739072);                      //      5,632
    int* bstartE = (int*)(ws + 24744704);                      //      2,560
    int* bstartV = (int*)(ws + 24747264);                      //      3,328
    int* e_off   = (int*)(ws + 24750592);                      //     80,128
    int* v_off   = (int*)(ws + 24830720);                      //    400,640
    float* Bm    = (float*)(ws + 25231360);                    //     16,384
    float* c2    = (float*)(ws + 25247744);                    //        256
    unsigned short* packA16 = (unsigned short*)(ws + 25248000);//      8,192
    unsigned short* packW16 = (unsigned short*)(ws + 25256192);//      8,192

    hipMemsetAsync(btot, 0, NBT * sizeof(int), stream);

    k_combine<<<17, 256, 0, stream>>>(W2w, W2bias, Ww, Bm, c2, packA16, packW16);
    k_hist<<<NCH, 256, 0, stream>>>(vertex, edges, He, Hv, btot);
    k_scan_tot<<<1, 1024, 0, stream>>>(btot, bstartE, bstartV);
    k_scan_chunks<<<NBT, 256, 0, stream>>>(He, Hv, bstartE, bstartV);
    k_scatter<<<NCH, 256, 0, stream>>>(vertex, edges, He, Hv, pairE, pairV);
    k_sortE<<<NBE, 256, 0, stream>>>(pairE, bstartE, e_off);
    k_sortV<<<NBV, 256, 0, stream>>>(pairV, bstartV, v_off);
    k_pre<<<(N_NODES + 63) / 64, 256, 0, stream>>>(X, X0, v_off, packA16, packW16,
                                                   c2, Wbias, X16, out);
    k_edge<<<N_EDGES / 4, 256, 0, stream>>>(e_off, pairE, (const unsigned int*)X16,
                                            W1w, W1b, Bm, Xe, Ye16);
    k_node<<<(N_NODES * 64) / 256, 256, 0, stream>>>(v_off, pairV, (const unsigned int*)Ye16, out);
}